// Round 1
// baseline (540.793 us; speedup 1.0000x reference)
//
#include <hip/hip_runtime.h>
#include <cstdint>
#include <cstddef>

#define L_SEQ 2048
#define DI 1024
#define DM 1024
#define RK 64
#define DS 16
#define NBC 32768      // 2*DI*DS columns (B|C)
#define NCHUNK 128
#define TCHUNK 16      // L_SEQ / NCHUNK

using f32x4  = __attribute__((ext_vector_type(4))) float;
using bf16x8 = __attribute__((ext_vector_type(8))) short;

typedef const __attribute__((address_space(1))) void gas_void;
typedef __attribute__((address_space(3))) void las_void;

#define GLL16(gp, lp) __builtin_amdgcn_global_load_lds( \
    (gas_void*)(uintptr_t)(gp), (las_void*)(uintptr_t)(lp), 16, 0, 0)

__device__ __forceinline__ unsigned short f2bf(float f) {
  unsigned u = __builtin_bit_cast(unsigned, f);
  u += 0x7fffu + ((u >> 16) & 1u);
  return (unsigned short)(u >> 16);
}
__device__ __forceinline__ float bflo(unsigned u) { return __builtin_bit_cast(float, u << 16); }
__device__ __forceinline__ float bfhi(unsigned u) { return __builtin_bit_cast(float, u & 0xffff0000u); }
__device__ __forceinline__ float softplusf(float z) {
  return (z > 20.f) ? z : log1pf(expf(z));
}

// ---------------- cast f32 -> bf16, 8 elems/thread ----------------
__global__ void cast_bf16_kernel(const float* __restrict__ in,
                                 unsigned short* __restrict__ out, int n8) {
  int i = blockIdx.x * blockDim.x + threadIdx.x;
  if (i >= n8) return;
  const f32x4* p = (const f32x4*)(in + (size_t)i * 8);
  f32x4 a = p[0], b = p[1];
  union { unsigned short us[8]; uint4 v; } r;
#pragma unroll
  for (int j = 0; j < 4; ++j) r.us[j] = f2bf(a[j]);
#pragma unroll
  for (int j = 0; j < 4; ++j) r.us[4 + j] = f2bf(b[j]);
  *(uint4*)(out + (size_t)i * 8) = r.v;
}

// ---------------- bf16 GEMM: C = A(MxK) * B(NxK)^T, m97 structure ----------------
template <bool OUT_BF16>
__global__ __launch_bounds__(256) void gemm_bt(
    const unsigned short* __restrict__ A,
    const unsigned short* __restrict__ Bm,
    void* __restrict__ Cv, int K, int ldc) {
  __shared__ unsigned short As[128 * 32];
  __shared__ unsigned short Bs[128 * 32];
  const int tid = threadIdx.x;
  const int lane = tid & 63;
  const int wave = tid >> 6;
  const int wm = (wave >> 1) * 64, wn = (wave & 1) * 64;
  const int m0 = blockIdx.y * 128, n0 = blockIdx.x * 128;
  const int lr = lane & 15, lk = (lane >> 4) * 8;

  const int srow = tid >> 2;
  const int scol = (tid & 3) * 8;
  const unsigned short* gA = A + (size_t)(m0 + srow) * K + scol;
  const unsigned short* gB = Bm + (size_t)(n0 + srow) * K + scol;
  unsigned short* lA0 = &As[tid * 8];
  unsigned short* lA1 = &As[2048 + tid * 8];
  unsigned short* lB0 = &Bs[tid * 8];
  unsigned short* lB1 = &Bs[2048 + tid * 8];

  f32x4 acc[4][4];
#pragma unroll
  for (int m = 0; m < 4; ++m)
#pragma unroll
    for (int n = 0; n < 4; ++n) acc[m][n] = f32x4{0.f, 0.f, 0.f, 0.f};

  for (int k0 = 0; k0 < K; k0 += 32) {
    GLL16(gA + k0, lA0);
    GLL16(gA + (size_t)64 * K + k0, lA1);
    GLL16(gB + k0, lB0);
    GLL16(gB + (size_t)64 * K + k0, lB1);
    __syncthreads();
    bf16x8 af[4], bfr[4];
#pragma unroll
    for (int m = 0; m < 4; ++m)
      af[m] = *(const bf16x8*)&As[(wm + m * 16 + lr) * 32 + lk];
#pragma unroll
    for (int n = 0; n < 4; ++n)
      bfr[n] = *(const bf16x8*)&Bs[(wn + n * 16 + lr) * 32 + lk];
#pragma unroll
    for (int m = 0; m < 4; ++m)
#pragma unroll
      for (int n = 0; n < 4; ++n)
        acc[m][n] = __builtin_amdgcn_mfma_f32_16x16x32_bf16(af[m], bfr[n], acc[m][n], 0, 0, 0);
    __syncthreads();
  }

  const int crow = (lane >> 4) * 4;
  const int ccol = lane & 15;
#pragma unroll
  for (int m = 0; m < 4; ++m)
#pragma unroll
    for (int n = 0; n < 4; ++n)
#pragma unroll
      for (int r = 0; r < 4; ++r) {
        int row = m0 + wm + m * 16 + crow + r;
        int col = n0 + wn + n * 16 + ccol;
        float v = acc[m][n][r];
        if (OUT_BF16)
          ((unsigned short*)Cv)[(size_t)row * ldc + col] = f2bf(v);
        else
          ((float*)Cv)[(size_t)row * ldc + col] = v;
      }
}

// ---------------- delta_lr = x @ W_in[0:64].T  (fp32, exact path) ----------------
__global__ __launch_bounds__(256) void delta_lr_kernel(
    const float* __restrict__ x, const float* __restrict__ Win,
    float* __restrict__ dlr) {
  __shared__ float xs[16][65];
  __shared__ float ws[64][65];
  const int tid = threadIdx.x;
  const int t0 = blockIdx.x * 16;
  const int r = tid & 63, tg = tid >> 6;
  float a0 = 0.f, a1 = 0.f, a2 = 0.f, a3 = 0.f;
  for (int k0 = 0; k0 < DM; k0 += 64) {
    {
      int row = tid >> 4, col = (tid & 15) * 4;
      f32x4 v = *(const f32x4*)&x[(size_t)(t0 + row) * DM + k0 + col];
      xs[row][col] = v.x; xs[row][col + 1] = v.y; xs[row][col + 2] = v.z; xs[row][col + 3] = v.w;
    }
#pragma unroll
    for (int p = 0; p < 4; ++p) {
      int idx = tid + p * 256;
      int row = idx >> 4, col = (idx & 15) * 4;
      f32x4 v = *(const f32x4*)&Win[(size_t)row * DM + k0 + col];
      ws[row][col] = v.x; ws[row][col + 1] = v.y; ws[row][col + 2] = v.z; ws[row][col + 3] = v.w;
    }
    __syncthreads();
#pragma unroll 16
    for (int kk = 0; kk < 64; ++kk) {
      float wv = ws[r][kk];
      a0 += xs[tg * 4 + 0][kk] * wv;
      a1 += xs[tg * 4 + 1][kk] * wv;
      a2 += xs[tg * 4 + 2][kk] * wv;
      a3 += xs[tg * 4 + 3][kk] * wv;
    }
    __syncthreads();
  }
  dlr[(size_t)(t0 + tg * 4 + 0) * RK + r] = a0;
  dlr[(size_t)(t0 + tg * 4 + 1) * RK + r] = a1;
  dlr[(size_t)(t0 + tg * 4 + 2) * RK + r] = a2;
  dlr[(size_t)(t0 + tg * 4 + 3) * RK + r] = a3;
}

// ---------------- delta = softplus(delta_lr @ W_delta.T)  (fp32) ----------------
__global__ __launch_bounds__(256) void delta_kernel(
    const float* __restrict__ dlr, const float* __restrict__ Wd,
    float* __restrict__ delta) {
  __shared__ float dl[16][65];
  __shared__ float wd[64][65];
  const int tid = threadIdx.x;
  const int i0 = blockIdx.x * 64;
  const int t0 = blockIdx.y * 16;
  const int il = tid & 63, tg = tid >> 6;
  {
    int row = tid >> 4, col = (tid & 15) * 4;
    f32x4 v = *(const f32x4*)&dlr[(size_t)(t0 + row) * RK + col];
    dl[row][col] = v.x; dl[row][col + 1] = v.y; dl[row][col + 2] = v.z; dl[row][col + 3] = v.w;
  }
#pragma unroll
  for (int p = 0; p < 4; ++p) {
    int idx = tid + p * 256;
    int row = idx >> 4, col = (idx & 15) * 4;
    f32x4 v = *(const f32x4*)&Wd[(size_t)(i0 + row) * RK + col];
    wd[row][col] = v.x; wd[row][col + 1] = v.y; wd[row][col + 2] = v.z; wd[row][col + 3] = v.w;
  }
  __syncthreads();
  float a0 = 0.f, a1 = 0.f, a2 = 0.f, a3 = 0.f;
#pragma unroll 16
  for (int kk = 0; kk < 64; ++kk) {
    float wv = wd[il][kk];
    a0 += dl[tg * 4 + 0][kk] * wv;
    a1 += dl[tg * 4 + 1][kk] * wv;
    a2 += dl[tg * 4 + 2][kk] * wv;
    a3 += dl[tg * 4 + 3][kk] * wv;
  }
  delta[(size_t)(t0 + tg * 4 + 0) * DI + i0 + il] = softplusf(a0);
  delta[(size_t)(t0 + tg * 4 + 1) * DI + i0 + il] = softplusf(a1);
  delta[(size_t)(t0 + tg * 4 + 2) * DI + i0 + il] = softplusf(a2);
  delta[(size_t)(t0 + tg * 4 + 3) * DI + i0 + il] = softplusf(a3);
}

// ---------------- scan pass 1: per-chunk local scan (h from 0), store h_end, P_end ----------------
__global__ __launch_bounds__(256) void scan_pass1(
    const float* __restrict__ delta, const float* __restrict__ x,
    const unsigned short* __restrict__ dbc, const float* __restrict__ A_log,
    float* __restrict__ h_end, float* __restrict__ P_end) {
  const int c = blockIdx.x >> 2;
  const int d = ((blockIdx.x & 3) << 8) + threadIdx.x;
  float Av[16];
#pragma unroll
  for (int q = 0; q < 4; ++q) {
    f32x4 v = *(const f32x4*)&A_log[(size_t)d * 16 + q * 4];
    Av[q * 4 + 0] = -expf(v.x); Av[q * 4 + 1] = -expf(v.y);
    Av[q * 4 + 2] = -expf(v.z); Av[q * 4 + 3] = -expf(v.w);
  }
  float h[16], P[16];
#pragma unroll
  for (int s = 0; s < 16; ++s) { h[s] = 0.f; P[s] = 1.f; }
  const int t0 = c * TCHUNK, t1 = t0 + TCHUNK;
  uint4 b0 = *(const uint4*)&dbc[(size_t)t0 * NBC + d * 16];
  uint4 b1 = *(const uint4*)&dbc[(size_t)t0 * NBC + d * 16 + 8];
  float dlt = delta[(size_t)t0 * DI + d];
  float xv = x[(size_t)t0 * DI + d];
  for (int t = t0; t < t1; ++t) {
    int tn = (t + 1 < t1) ? t + 1 : t;
    uint4 nb0 = *(const uint4*)&dbc[(size_t)tn * NBC + d * 16];
    uint4 nb1 = *(const uint4*)&dbc[(size_t)tn * NBC + d * 16 + 8];
    float ndlt = delta[(size_t)tn * DI + d];
    float nxv = x[(size_t)tn * DI + d];
    float du = dlt * xv;
    unsigned bu[8] = {b0.x, b0.y, b0.z, b0.w, b1.x, b1.y, b1.z, b1.w};
#pragma unroll
    for (int s = 0; s < 16; ++s) {
      float dA = __expf(dlt * Av[s]);
      float Bv = (s & 1) ? bfhi(bu[s >> 1]) : bflo(bu[s >> 1]);
      h[s] = dA * h[s] + du * Bv;
      P[s] *= dA;
    }
    b0 = nb0; b1 = nb1; dlt = ndlt; xv = nxv;
  }
  float* he = &h_end[((size_t)c * DI + d) * 16];
  float* pe = &P_end[((size_t)c * DI + d) * 16];
#pragma unroll
  for (int q = 0; q < 4; ++q) {
    f32x4 vh = {h[q * 4 + 0], h[q * 4 + 1], h[q * 4 + 2], h[q * 4 + 3]};
    f32x4 vp = {P[q * 4 + 0], P[q * 4 + 1], P[q * 4 + 2], P[q * 4 + 3]};
    *(f32x4*)&he[q * 4] = vh;
    *(f32x4*)&pe[q * 4] = vp;
  }
}

// ---------------- scan pass 2: combine chunk boundaries ----------------
__global__ void scan_pass2(const float* __restrict__ h_end,
                           const float* __restrict__ P_end,
                           float* __restrict__ h_in) {
  const int j = blockIdx.x * 256 + threadIdx.x;  // 0 .. DI*DS-1
  const int NS = DI * DS;
  float h = 0.f;
  for (int c = 0; c < NCHUNK; c += 4) {
    float P0 = P_end[(size_t)(c + 0) * NS + j], H0 = h_end[(size_t)(c + 0) * NS + j];
    float P1 = P_end[(size_t)(c + 1) * NS + j], H1 = h_end[(size_t)(c + 1) * NS + j];
    float P2 = P_end[(size_t)(c + 2) * NS + j], H2 = h_end[(size_t)(c + 2) * NS + j];
    float P3 = P_end[(size_t)(c + 3) * NS + j], H3 = h_end[(size_t)(c + 3) * NS + j];
    h_in[(size_t)(c + 0) * NS + j] = h; h = P0 * h + H0;
    h_in[(size_t)(c + 1) * NS + j] = h; h = P1 * h + H1;
    h_in[(size_t)(c + 2) * NS + j] = h; h = P2 * h + H2;
    h_in[(size_t)(c + 3) * NS + j] = h; h = P3 * h + H3;
  }
}

// ---------------- scan pass 3: full scan from h_in, emit y (bf16) ----------------
__global__ __launch_bounds__(256) void scan_pass3(
    const float* __restrict__ delta, const float* __restrict__ x,
    const unsigned short* __restrict__ dbc, const float* __restrict__ A_log,
    const float* __restrict__ Dvec, const float* __restrict__ h_in,
    unsigned short* __restrict__ ybf) {
  const int c = blockIdx.x >> 2;
  const int d = ((blockIdx.x & 3) << 8) + threadIdx.x;
  float Av[16];
#pragma unroll
  for (int q = 0; q < 4; ++q) {
    f32x4 v = *(const f32x4*)&A_log[(size_t)d * 16 + q * 4];
    Av[q * 4 + 0] = -expf(v.x); Av[q * 4 + 1] = -expf(v.y);
    Av[q * 4 + 2] = -expf(v.z); Av[q * 4 + 3] = -expf(v.w);
  }
  const float Df = Dvec[d];
  float h[16];
  const float* hi = &h_in[((size_t)c * DI + d) * 16];
#pragma unroll
  for (int q = 0; q < 4; ++q) {
    f32x4 v = *(const f32x4*)&hi[q * 4];
    h[q * 4 + 0] = v.x; h[q * 4 + 1] = v.y; h[q * 4 + 2] = v.z; h[q * 4 + 3] = v.w;
  }
  const int t0 = c * TCHUNK, t1 = t0 + TCHUNK;
  uint4 b0 = *(const uint4*)&dbc[(size_t)t0 * NBC + d * 16];
  uint4 b1 = *(const uint4*)&dbc[(size_t)t0 * NBC + d * 16 + 8];
  uint4 c0 = *(const uint4*)&dbc[(size_t)t0 * NBC + DI * DS + d * 16];
  uint4 c1 = *(const uint4*)&dbc[(size_t)t0 * NBC + DI * DS + d * 16 + 8];
  float dlt = delta[(size_t)t0 * DI + d];
  float xv = x[(size_t)t0 * DI + d];
  for (int t = t0; t < t1; ++t) {
    int tn = (t + 1 < t1) ? t + 1 : t;
    uint4 nb0 = *(const uint4*)&dbc[(size_t)tn * NBC + d * 16];
    uint4 nb1 = *(const uint4*)&dbc[(size_t)tn * NBC + d * 16 + 8];
    uint4 nc0 = *(const uint4*)&dbc[(size_t)tn * NBC + DI * DS + d * 16];
    uint4 nc1 = *(const uint4*)&dbc[(size_t)tn * NBC + DI * DS + d * 16 + 8];
    float ndlt = delta[(size_t)tn * DI + d];
    float nxv = x[(size_t)tn * DI + d];
    float du = dlt * xv;
    unsigned bu[8] = {b0.x, b0.y, b0.z, b0.w, b1.x, b1.y, b1.z, b1.w};
    unsigned cu[8] = {c0.x, c0.y, c0.z, c0.w, c1.x, c1.y, c1.z, c1.w};
    float yacc = 0.f;
#pragma unroll
    for (int s = 0; s < 16; ++s) {
      float dA = __expf(dlt * Av[s]);
      float Bv = (s & 1) ? bfhi(bu[s >> 1]) : bflo(bu[s >> 1]);
      float Cv = (s & 1) ? bfhi(cu[s >> 1]) : bflo(cu[s >> 1]);
      h[s] = dA * h[s] + du * Bv;
      yacc += h[s] * Cv;
    }
    ybf[(size_t)t * DI + d] = f2bf(yacc + xv * Df);
    b0 = nb0; b1 = nb1; c0 = nc0; c1 = nc1; dlt = ndlt; xv = nxv;
  }
}

// ---------------- launch ----------------
extern "C" void kernel_launch(void* const* d_in, const int* in_sizes, int n_in,
                              void* d_out, int out_size, void* d_ws, size_t ws_size,
                              hipStream_t stream) {
  const float* x    = (const float*)d_in[0];
  const float* Win  = (const float*)d_in[1];
  const float* Wd   = (const float*)d_in[2];
  const float* Alog = (const float*)d_in[3];
  const float* Dv   = (const float*)d_in[4];
  const float* Wout = (const float*)d_in[5];
  float* out = (float*)d_out;

  char* ws = (char*)d_ws;
  size_t off = 0;
  auto walloc = [&](size_t bytes) -> void* {
    void* p = ws + off;
    off += (bytes + 255) & ~(size_t)255;
    return p;
  };
  unsigned short* x_bf    = (unsigned short*)walloc((size_t)L_SEQ * DI * 2);
  unsigned short* Wbc_bf  = (unsigned short*)walloc((size_t)NBC * DM * 2);
  unsigned short* Wout_bf = (unsigned short*)walloc((size_t)DM * DI * 2);
  unsigned short* dbc     = (unsigned short*)walloc((size_t)L_SEQ * NBC * 2);
  float* dlr   = (float*)walloc((size_t)L_SEQ * RK * 4);
  float* delta = (float*)walloc((size_t)L_SEQ * DI * 4);
  unsigned short* y_bf = (unsigned short*)walloc((size_t)L_SEQ * DI * 2);
  float* h_end = (float*)walloc((size_t)NCHUNK * DI * DS * 4);
  float* P_end = (float*)walloc((size_t)NCHUNK * DI * DS * 4);
  float* h_in  = (float*)walloc((size_t)NCHUNK * DI * DS * 4);

  // casts
  cast_bf16_kernel<<<(L_SEQ * DI / 8 + 255) / 256, 256, 0, stream>>>(x, x_bf, L_SEQ * DI / 8);
  cast_bf16_kernel<<<((size_t)NBC * DM / 8 + 255) / 256, 256, 0, stream>>>(
      Win + (size_t)RK * DM, Wbc_bf, NBC * DM / 8);
  cast_bf16_kernel<<<(DM * DI / 8 + 255) / 256, 256, 0, stream>>>(Wout, Wout_bf, DM * DI / 8);

  // fp32 delta path
  delta_lr_kernel<<<L_SEQ / 16, 256, 0, stream>>>(x, Win, dlr);
  delta_kernel<<<dim3(DI / 64, L_SEQ / 16), 256, 0, stream>>>(dlr, Wd, delta);

  // big bf16 GEMM: dbc(B|C) = x @ W_in[64:].T
  gemm_bt<true><<<dim3(NBC / 128, L_SEQ / 128), 256, 0, stream>>>(x_bf, Wbc_bf, dbc, DM, NBC);

  // chunked scan
  scan_pass1<<<NCHUNK * 4, 256, 0, stream>>>(delta, x, dbc, Alog, h_end, P_end);
  scan_pass2<<<DI * DS / 256, 256, 0, stream>>>(h_end, P_end, h_in);
  scan_pass3<<<NCHUNK * 4, 256, 0, stream>>>(delta, x, dbc, Alog, Dv, h_in, y_bf);

  // output GEMM: out = y @ W_out.T
  gemm_bt<false><<<dim3(DI / 128, L_SEQ / 128), 256, 0, stream>>>(y_bf, Wout_bf, out, DM, DI);
}

// Round 3
// 506.346 us; speedup vs baseline: 1.0680x; 1.0680x over previous
//
#include <hip/hip_runtime.h>
#include <cstdint>
#include <cstddef>

#define L_SEQ 2048
#define DI 1024
#define DM 1024
#define RK 64
#define DS 16
#define NBC 32768      // 2*DI*DS columns (B|C)
#define NCHUNK 128
#define TCHUNK 16      // L_SEQ / NCHUNK

using f32x4  = __attribute__((ext_vector_type(4))) float;
using bf16x8 = __attribute__((ext_vector_type(8))) short;

typedef const __attribute__((address_space(1))) void gas_void;
typedef __attribute__((address_space(3))) void las_void;

#define GLL16(gp, lp) __builtin_amdgcn_global_load_lds( \
    (gas_void*)(uintptr_t)(gp), (las_void*)(uintptr_t)(lp), 16, 0, 0)

#define VMCNT(n) asm volatile("s_waitcnt vmcnt(" #n ")" ::: "memory")

__device__ __forceinline__ unsigned short f2bf(float f) {
  unsigned u = __builtin_bit_cast(unsigned, f);
  u += 0x7fffu + ((u >> 16) & 1u);
  return (unsigned short)(u >> 16);
}
__device__ __forceinline__ float bflo(unsigned u) { return __builtin_bit_cast(float, u << 16); }
__device__ __forceinline__ float bfhi(unsigned u) { return __builtin_bit_cast(float, u & 0xffff0000u); }
__device__ __forceinline__ float softplusf(float z) {
  return (z > 20.f) ? z : log1pf(expf(z));
}

// ---------------- cast f32 -> bf16, 8 elems/thread ----------------
__global__ void cast_bf16_kernel(const float* __restrict__ in,
                                 unsigned short* __restrict__ out, int n8) {
  int i = blockIdx.x * blockDim.x + threadIdx.x;
  if (i >= n8) return;
  const f32x4* p = (const f32x4*)(in + (size_t)i * 8);
  f32x4 a = p[0], b = p[1];
  union { unsigned short us[8]; uint4 v; } r;
#pragma unroll
  for (int j = 0; j < 4; ++j) r.us[j] = f2bf(a[j]);
#pragma unroll
  for (int j = 0; j < 4; ++j) r.us[4 + j] = f2bf(b[j]);
  *(uint4*)(out + (size_t)i * 8) = r.v;
}

// ================= big GEMM: dbc = x(2048x1024) @ Wbc(32768x1024)^T =================
// 256x256 tile, 8 waves (2Mx4N, 128x64 per wave), BK=32, 4-deep LDS ring (128 KiB),
// XOR-swizzle (involution, both-sides), T4 counted vmcnt(8), T5 setprio,
// T1 bijective XCD swizzle (1024 WGs % 8 == 0).
__global__ __launch_bounds__(512, 2) void gemm_big(
    const unsigned short* __restrict__ A,
    const unsigned short* __restrict__ Bm,
    unsigned short* __restrict__ C) {
  constexpr int K = 1024;
  constexpr int KT = 32;       // K-tiles of 32
  constexpr int LDC = NBC;
  constexpr int GRID_N = 128;  // 32768/256
  __shared__ unsigned short lds[65536];  // 4 bufs x (A 16KB + B 16KB) = 128 KiB

  const int tid = threadIdx.x;
  const int lane = tid & 63;
  const int wave = tid >> 6;
  const int wm = (wave >> 2) * 128;   // 2 M-wave-groups
  const int wn = (wave & 3) * 64;     // 4 N-wave-groups
  const int lr = lane & 15;
  const int lkx = ((lane >> 4) ^ (lr & 3)) << 4;  // swizzled in-row byte offset

  // bijective XCD swizzle: contiguous chunk per XCD
  const int b = blockIdx.x;
  const int per = gridDim.x >> 3;
  const int sw = (b & 7) * per + (b >> 3);
  const int m0 = (sw / GRID_N) * 256;
  const int n0 = (sw % GRID_N) * 256;

  // staging: thread t covers row r0 = t>>2 (of a 128-row half), slot t&3;
  // source col pre-swizzled so linear LDS dest + swizzled read are consistent.
  const int r0 = tid >> 2;
  const int colsw = 8 * ((tid & 3) ^ (r0 & 3));
  const unsigned short* gA0 = A + (size_t)(m0 + r0) * K + colsw;
  const unsigned short* gA1 = gA0 + (size_t)128 * K;
  const unsigned short* gB0 = Bm + (size_t)(n0 + r0) * K + colsw;
  const unsigned short* gB1 = gB0 + (size_t)128 * K;

  f32x4 acc[8][4];
#pragma unroll
  for (int m = 0; m < 8; ++m)
#pragma unroll
    for (int n = 0; n < 4; ++n) acc[m][n] = f32x4{0.f, 0.f, 0.f, 0.f};

  auto stage = [&](int buf, int kt) {
    const int kofs = kt * 32;
    unsigned short* d = &lds[buf * 16384 + tid * 8];
    GLL16(gA0 + kofs, d);            // A half 0 (rows 0-127)
    GLL16(gA1 + kofs, d + 4096);     // A half 1 (rows 128-255)
    GLL16(gB0 + kofs, d + 8192);     // B half 0
    GLL16(gB1 + kofs, d + 12288);    // B half 1
  };

  auto compute = [&](int buf) {
    const char* base = (const char*)lds + (size_t)buf * 32768;
    bf16x8 af[8], bv[4];
#pragma unroll
    for (int m = 0; m < 8; ++m)
      af[m] = *(const bf16x8*)(base + (wm + m * 16 + lr) * 64 + lkx);
#pragma unroll
    for (int n = 0; n < 4; ++n)
      bv[n] = *(const bf16x8*)(base + 16384 + (wn + n * 16 + lr) * 64 + lkx);
    __builtin_amdgcn_s_setprio(1);
#pragma unroll
    for (int m = 0; m < 8; ++m)
#pragma unroll
      for (int n = 0; n < 4; ++n)
        acc[m][n] = __builtin_amdgcn_mfma_f32_16x16x32_bf16(af[m], bv[n], acc[m][n], 0, 0, 0);
    __builtin_amdgcn_s_setprio(0);
  };

  // prologue: 3 tiles in flight, wait for tile 0 (12 issued, vmcnt(8) -> oldest 4 done)
  stage(0, 0);
  stage(1, 1);
  stage(2, 2);
  VMCNT(8);
  __builtin_amdgcn_s_barrier();
  __builtin_amdgcn_sched_barrier(0);

#pragma unroll 4
  for (int t = 0; t < KT - 3; ++t) {
    stage((t + 3) & 3, t + 3);   // writes buffer last read at t-1 (barrier-protected)
    compute(t & 3);
    VMCNT(8);                    // tiles {t+2,t+3} may remain in flight; t+1 landed
    __builtin_amdgcn_s_barrier();
    __builtin_amdgcn_sched_barrier(0);
  }
  compute((KT - 3) & 3);
  VMCNT(4);
  __builtin_amdgcn_s_barrier();
  __builtin_amdgcn_sched_barrier(0);
  compute((KT - 2) & 3);
  VMCNT(0);
  __builtin_amdgcn_s_barrier();
  __builtin_amdgcn_sched_barrier(0);
  compute((KT - 1) & 3);

  // epilogue: C/D mapping col=lane&15, row=(lane>>4)*4+r (m89/m91-verified)
  const int crow = (lane >> 4) * 4;
#pragma unroll
  for (int m = 0; m < 8; ++m)
#pragma unroll
    for (int n = 0; n < 4; ++n)
#pragma unroll
      for (int r = 0; r < 4; ++r) {
        int row = m0 + wm + m * 16 + crow + r;
        int col = n0 + wn + n * 16 + lr;
        C[(size_t)row * LDC + col] = f2bf(acc[m][n][r]);
      }
}

// ---------------- bf16 GEMM (m97 structure), kept for the small output GEMM ----------------
template <bool OUT_BF16>
__global__ __launch_bounds__(256) void gemm_bt(
    const unsigned short* __restrict__ A,
    const unsigned short* __restrict__ Bm,
    void* __restrict__ Cv, int K, int ldc) {
  __shared__ unsigned short As[128 * 32];
  __shared__ unsigned short Bs[128 * 32];
  const int tid = threadIdx.x;
  const int lane = tid & 63;
  const int wave = tid >> 6;
  const int wm = (wave >> 1) * 64, wn = (wave & 1) * 64;
  const int m0 = blockIdx.y * 128, n0 = blockIdx.x * 128;
  const int lr = lane & 15, lk = (lane >> 4) * 8;

  const int srow = tid >> 2;
  const int scol = (tid & 3) * 8;
  const unsigned short* gA = A + (size_t)(m0 + srow) * K + scol;
  const unsigned short* gB = Bm + (size_t)(n0 + srow) * K + scol;
  unsigned short* lA0 = &As[tid * 8];
  unsigned short* lA1 = &As[2048 + tid * 8];
  unsigned short* lB0 = &Bs[tid * 8];
  unsigned short* lB1 = &Bs[2048 + tid * 8];

  f32x4 acc[4][4];
#pragma unroll
  for (int m = 0; m < 4; ++m)
#pragma unroll
    for (int n = 0; n < 4; ++n) acc[m][n] = f32x4{0.f, 0.f, 0.f, 0.f};

  for (int k0 = 0; k0 < K; k0 += 32) {
    GLL16(gA + k0, lA0);
    GLL16(gA + (size_t)64 * K + k0, lA1);
    GLL16(gB + k0, lB0);
    GLL16(gB + (size_t)64 * K + k0, lB1);
    __syncthreads();
    bf16x8 af[4], bfr[4];
#pragma unroll
    for (int m = 0; m < 4; ++m)
      af[m] = *(const bf16x8*)&As[(wm + m * 16 + lr) * 32 + lk];
#pragma unroll
    for (int n = 0; n < 4; ++n)
      bfr[n] = *(const bf16x8*)&Bs[(wn + n * 16 + lr) * 32 + lk];
#pragma unroll
    for (int m = 0; m < 4; ++m)
#pragma unroll
      for (int n = 0; n < 4; ++n)
        acc[m][n] = __builtin_amdgcn_mfma_f32_16x16x32_bf16(af[m], bfr[n], acc[m][n], 0, 0, 0);
    __syncthreads();
  }

  const int crow = (lane >> 4) * 4;
  const int ccol = lane & 15;
#pragma unroll
  for (int m = 0; m < 4; ++m)
#pragma unroll
    for (int n = 0; n < 4; ++n)
#pragma unroll
      for (int r = 0; r < 4; ++r) {
        int row = m0 + wm + m * 16 + crow + r;
        int col = n0 + wn + n * 16 + ccol;
        float v = acc[m][n][r];
        if (OUT_BF16)
          ((unsigned short*)Cv)[(size_t)row * ldc + col] = f2bf(v);
        else
          ((float*)Cv)[(size_t)row * ldc + col] = v;
      }
}

// ---------------- delta_lr = x @ W_in[0:64].T  (fp32, exact path) ----------------
__global__ __launch_bounds__(256) void delta_lr_kernel(
    const float* __restrict__ x, const float* __restrict__ Win,
    float* __restrict__ dlr) {
  __shared__ float xs[16][65];
  __shared__ float ws[64][65];
  const int tid = threadIdx.x;
  const int t0 = blockIdx.x * 16;
  const int r = tid & 63, tg = tid >> 6;
  float a0 = 0.f, a1 = 0.f, a2 = 0.f, a3 = 0.f;
  for (int k0 = 0; k0 < DM; k0 += 64) {
    {
      int row = tid >> 4, col = (tid & 15) * 4;
      f32x4 v = *(const f32x4*)&x[(size_t)(t0 + row) * DM + k0 + col];
      xs[row][col] = v.x; xs[row][col + 1] = v.y; xs[row][col + 2] = v.z; xs[row][col + 3] = v.w;
    }
#pragma unroll
    for (int p = 0; p < 4; ++p) {
      int idx = tid + p * 256;
      int row = idx >> 4, col = (idx & 15) * 4;
      f32x4 v = *(const f32x4*)&Win[(size_t)row * DM + k0 + col];
      ws[row][col] = v.x; ws[row][col + 1] = v.y; ws[row][col + 2] = v.z; ws[row][col + 3] = v.w;
    }
    __syncthreads();
#pragma unroll 16
    for (int kk = 0; kk < 64; ++kk) {
      float wv = ws[r][kk];
      a0 += xs[tg * 4 + 0][kk] * wv;
      a1 += xs[tg * 4 + 1][kk] * wv;
      a2 += xs[tg * 4 + 2][kk] * wv;
      a3 += xs[tg * 4 + 3][kk] * wv;
    }
    __syncthreads();
  }
  dlr[(size_t)(t0 + tg * 4 + 0) * RK + r] = a0;
  dlr[(size_t)(t0 + tg * 4 + 1) * RK + r] = a1;
  dlr[(size_t)(t0 + tg * 4 + 2) * RK + r] = a2;
  dlr[(size_t)(t0 + tg * 4 + 3) * RK + r] = a3;
}

// ---------------- delta = softplus(delta_lr @ W_delta.T)  (fp32) ----------------
__global__ __launch_bounds__(256) void delta_kernel(
    const float* __restrict__ dlr, const float* __restrict__ Wd,
    float* __restrict__ delta) {
  __shared__ float dl[16][65];
  __shared__ float wd[64][65];
  const int tid = threadIdx.x;
  const int i0 = blockIdx.x * 64;
  const int t0 = blockIdx.y * 16;
  const int il = tid & 63, tg = tid >> 6;
  {
    int row = tid >> 4, col = (tid & 15) * 4;
    f32x4 v = *(const f32x4*)&dlr[(size_t)(t0 + row) * RK + col];
    dl[row][col] = v.x; dl[row][col + 1] = v.y; dl[row][col + 2] = v.z; dl[row][col + 3] = v.w;
  }
#pragma unroll
  for (int p = 0; p < 4; ++p) {
    int idx = tid + p * 256;
    int row = idx >> 4, col = (idx & 15) * 4;
    f32x4 v = *(const f32x4*)&Wd[(size_t)(i0 + row) * RK + col];
    wd[row][col] = v.x; wd[row][col + 1] = v.y; wd[row][col + 2] = v.z; wd[row][col + 3] = v.w;
  }
  __syncthreads();
  float a0 = 0.f, a1 = 0.f, a2 = 0.f, a3 = 0.f;
#pragma unroll 16
  for (int kk = 0; kk < 64; ++kk) {
    float wv = wd[il][kk];
    a0 += dl[tg * 4 + 0][kk] * wv;
    a1 += dl[tg * 4 + 1][kk] * wv;
    a2 += dl[tg * 4 + 2][kk] * wv;
    a3 += dl[tg * 4 + 3][kk] * wv;
  }
  delta[(size_t)(t0 + tg * 4 + 0) * DI + i0 + il] = softplusf(a0);
  delta[(size_t)(t0 + tg * 4 + 1) * DI + i0 + il] = softplusf(a1);
  delta[(size_t)(t0 + tg * 4 + 2) * DI + i0 + il] = softplusf(a2);
  delta[(size_t)(t0 + tg * 4 + 3) * DI + i0 + il] = softplusf(a3);
}

// ---------------- scan pass 1: per-chunk local scan (h from 0), store h_end, P_end ----------------
__global__ __launch_bounds__(256) void scan_pass1(
    const float* __restrict__ delta, const float* __restrict__ x,
    const unsigned short* __restrict__ dbc, const float* __restrict__ A_log,
    float* __restrict__ h_end, float* __restrict__ P_end) {
  const int c = blockIdx.x >> 2;
  const int d = ((blockIdx.x & 3) << 8) + threadIdx.x;
  float Av[16];
#pragma unroll
  for (int q = 0; q < 4; ++q) {
    f32x4 v = *(const f32x4*)&A_log[(size_t)d * 16 + q * 4];
    Av[q * 4 + 0] = -expf(v.x); Av[q * 4 + 1] = -expf(v.y);
    Av[q * 4 + 2] = -expf(v.z); Av[q * 4 + 3] = -expf(v.w);
  }
  float h[16], P[16];
#pragma unroll
  for (int s = 0; s < 16; ++s) { h[s] = 0.f; P[s] = 1.f; }
  const int t0 = c * TCHUNK, t1 = t0 + TCHUNK;
  uint4 b0 = *(const uint4*)&dbc[(size_t)t0 * NBC + d * 16];
  uint4 b1 = *(const uint4*)&dbc[(size_t)t0 * NBC + d * 16 + 8];
  float dlt = delta[(size_t)t0 * DI + d];
  float xv = x[(size_t)t0 * DI + d];
  for (int t = t0; t < t1; ++t) {
    int tn = (t + 1 < t1) ? t + 1 : t;
    uint4 nb0 = *(const uint4*)&dbc[(size_t)tn * NBC + d * 16];
    uint4 nb1 = *(const uint4*)&dbc[(size_t)tn * NBC + d * 16 + 8];
    float ndlt = delta[(size_t)tn * DI + d];
    float nxv = x[(size_t)tn * DI + d];
    float du = dlt * xv;
    unsigned bu[8] = {b0.x, b0.y, b0.z, b0.w, b1.x, b1.y, b1.z, b1.w};
#pragma unroll
    for (int s = 0; s < 16; ++s) {
      float dA = __expf(dlt * Av[s]);
      float Bv = (s & 1) ? bfhi(bu[s >> 1]) : bflo(bu[s >> 1]);
      h[s] = dA * h[s] + du * Bv;
      P[s] *= dA;
    }
    b0 = nb0; b1 = nb1; dlt = ndlt; xv = nxv;
  }
  float* he = &h_end[((size_t)c * DI + d) * 16];
  float* pe = &P_end[((size_t)c * DI + d) * 16];
#pragma unroll
  for (int q = 0; q < 4; ++q) {
    f32x4 vh = {h[q * 4 + 0], h[q * 4 + 1], h[q * 4 + 2], h[q * 4 + 3]};
    f32x4 vp = {P[q * 4 + 0], P[q * 4 + 1], P[q * 4 + 2], P[q * 4 + 3]};
    *(f32x4*)&he[q * 4] = vh;
    *(f32x4*)&pe[q * 4] = vp;
  }
}

// ---------------- scan pass 2: combine chunk boundaries ----------------
__global__ void scan_pass2(const float* __restrict__ h_end,
                           const float* __restrict__ P_end,
                           float* __restrict__ h_in) {
  const int j = blockIdx.x * 256 + threadIdx.x;  // 0 .. DI*DS-1
  const int NS = DI * DS;
  float h = 0.f;
  for (int c = 0; c < NCHUNK; c += 4) {
    float P0 = P_end[(size_t)(c + 0) * NS + j], H0 = h_end[(size_t)(c + 0) * NS + j];
    float P1 = P_end[(size_t)(c + 1) * NS + j], H1 = h_end[(size_t)(c + 1) * NS + j];
    float P2 = P_end[(size_t)(c + 2) * NS + j], H2 = h_end[(size_t)(c + 2) * NS + j];
    float P3 = P_end[(size_t)(c + 3) * NS + j], H3 = h_end[(size_t)(c + 3) * NS + j];
    h_in[(size_t)(c + 0) * NS + j] = h; h = P0 * h + H0;
    h_in[(size_t)(c + 1) * NS + j] = h; h = P1 * h + H1;
    h_in[(size_t)(c + 2) * NS + j] = h; h = P2 * h + H2;
    h_in[(size_t)(c + 3) * NS + j] = h; h = P3 * h + H3;
  }
}

// ---------------- scan pass 3: full scan from h_in, emit y (bf16) ----------------
__global__ __launch_bounds__(256) void scan_pass3(
    const float* __restrict__ delta, const float* __restrict__ x,
    const unsigned short* __restrict__ dbc, const float* __restrict__ A_log,
    const float* __restrict__ Dvec, const float* __restrict__ h_in,
    unsigned short* __restrict__ ybf) {
  const int c = blockIdx.x >> 2;
  const int d = ((blockIdx.x & 3) << 8) + threadIdx.x;
  float Av[16];
#pragma unroll
  for (int q = 0; q < 4; ++q) {
    f32x4 v = *(const f32x4*)&A_log[(size_t)d * 16 + q * 4];
    Av[q * 4 + 0] = -expf(v.x); Av[q * 4 + 1] = -expf(v.y);
    Av[q * 4 + 2] = -expf(v.z); Av[q * 4 + 3] = -expf(v.w);
  }
  const float Df = Dvec[d];
  float h[16];
  const float* hi = &h_in[((size_t)c * DI + d) * 16];
#pragma unroll
  for (int q = 0; q < 4; ++q) {
    f32x4 v = *(const f32x4*)&hi[q * 4];
    h[q * 4 + 0] = v.x; h[q * 4 + 1] = v.y; h[q * 4 + 2] = v.z; h[q * 4 + 3] = v.w;
  }
  const int t0 = c * TCHUNK, t1 = t0 + TCHUNK;
  uint4 b0 = *(const uint4*)&dbc[(size_t)t0 * NBC + d * 16];
  uint4 b1 = *(const uint4*)&dbc[(size_t)t0 * NBC + d * 16 + 8];
  uint4 c0 = *(const uint4*)&dbc[(size_t)t0 * NBC + DI * DS + d * 16];
  uint4 c1 = *(const uint4*)&dbc[(size_t)t0 * NBC + DI * DS + d * 16 + 8];
  float dlt = delta[(size_t)t0 * DI + d];
  float xv = x[(size_t)t0 * DI + d];
  for (int t = t0; t < t1; ++t) {
    int tn = (t + 1 < t1) ? t + 1 : t;
    uint4 nb0 = *(const uint4*)&dbc[(size_t)tn * NBC + d * 16];
    uint4 nb1 = *(const uint4*)&dbc[(size_t)tn * NBC + d * 16 + 8];
    uint4 nc0 = *(const uint4*)&dbc[(size_t)tn * NBC + DI * DS + d * 16];
    uint4 nc1 = *(const uint4*)&dbc[(size_t)tn * NBC + DI * DS + d * 16 + 8];
    float ndlt = delta[(size_t)tn * DI + d];
    float nxv = x[(size_t)tn * DI + d];
    float du = dlt * xv;
    unsigned bu[8] = {b0.x, b0.y, b0.z, b0.w, b1.x, b1.y, b1.z, b1.w};
    unsigned cu[8] = {c0.x, c0.y, c0.z, c0.w, c1.x, c1.y, c1.z, c1.w};
    float yacc = 0.f;
#pragma unroll
    for (int s = 0; s < 16; ++s) {
      float dA = __expf(dlt * Av[s]);
      float Bv = (s & 1) ? bfhi(bu[s >> 1]) : bflo(bu[s >> 1]);
      float Cv = (s & 1) ? bfhi(cu[s >> 1]) : bflo(cu[s >> 1]);
      h[s] = dA * h[s] + du * Bv;
      yacc += h[s] * Cv;
    }
    ybf[(size_t)t * DI + d] = f2bf(yacc + xv * Df);
    b0 = nb0; b1 = nb1; c0 = nc0; c1 = nc1; dlt = ndlt; xv = nxv;
  }
}

// ---------------- launch ----------------
extern "C" void kernel_launch(void* const* d_in, const int* in_sizes, int n_in,
                              void* d_out, int out_size, void* d_ws, size_t ws_size,
                              hipStream_t stream) {
  const float* x    = (const float*)d_in[0];
  const float* Win  = (const float*)d_in[1];
  const float* Wd   = (const float*)d_in[2];
  const float* Alog = (const float*)d_in[3];
  const float* Dv   = (const float*)d_in[4];
  const float* Wout = (const float*)d_in[5];
  float* out = (float*)d_out;

  char* ws = (char*)d_ws;
  size_t off = 0;
  auto walloc = [&](size_t bytes) -> void* {
    void* p = ws + off;
    off += (bytes + 255) & ~(size_t)255;
    return p;
  };
  unsigned short* x_bf    = (unsigned short*)walloc((size_t)L_SEQ * DI * 2);
  unsigned short* Wbc_bf  = (unsigned short*)walloc((size_t)NBC * DM * 2);
  unsigned short* Wout_bf = (unsigned short*)walloc((size_t)DM * DI * 2);
  unsigned short* dbc     = (unsigned short*)walloc((size_t)L_SEQ * NBC * 2);
  float* dlr   = (float*)walloc((size_t)L_SEQ * RK * 4);
  float* delta = (float*)walloc((size_t)L_SEQ * DI * 4);
  unsigned short* y_bf = (unsigned short*)walloc((size_t)L_SEQ * DI * 2);
  float* h_end = (float*)walloc((size_t)NCHUNK * DI * DS * 4);
  float* P_end = (float*)walloc((size_t)NCHUNK * DI * DS * 4);
  float* h_in  = (float*)walloc((size_t)NCHUNK * DI * DS * 4);

  // casts
  cast_bf16_kernel<<<(L_SEQ * DI / 8 + 255) / 256, 256, 0, stream>>>(x, x_bf, L_SEQ * DI / 8);
  cast_bf16_kernel<<<((size_t)NBC * DM / 8 + 255) / 256, 256, 0, stream>>>(
      Win + (size_t)RK * DM, Wbc_bf, NBC * DM / 8);
  cast_bf16_kernel<<<(DM * DI / 8 + 255) / 256, 256, 0, stream>>>(Wout, Wout_bf, DM * DI / 8);

  // fp32 delta path
  delta_lr_kernel<<<L_SEQ / 16, 256, 0, stream>>>(x, Win, dlr);
  delta_kernel<<<dim3(DI / 64, L_SEQ / 16), 256, 0, stream>>>(dlr, Wd, delta);

  // big bf16 GEMM: dbc(B|C) = x @ W_in[64:].T   (256^2 tile, 8-wave, ring-buffered)
  gemm_big<<<(L_SEQ / 256) * (NBC / 256), 512, 0, stream>>>(x_bf, Wbc_bf, dbc);

  // chunked scan
  scan_pass1<<<NCHUNK * 4, 256, 0, stream>>>(delta, x, dbc, Alog, h_end, P_end);
  scan_pass2<<<DI * DS / 256, 256, 0, stream>>>(h_end, P_end, h_in);
  scan_pass3<<<NCHUNK * 4, 256, 0, stream>>>(delta, x, dbc, Alog, Dv, h_in, y_bf);

  // output GEMM: out = y @ W_out.T
  gemm_bt<false><<<dim3(DI / 128, L_SEQ / 128), 256, 0, stream>>>(y_bf, Wout_bf, out, DM, DI);
}

// Round 4
// 494.909 us; speedup vs baseline: 1.0927x; 1.0231x over previous
//
#include <hip/hip_runtime.h>
#include <cstdint>
#include <cstddef>

#define L_SEQ 2048
#define DI 1024
#define DM 1024
#define RK 64
#define DS 16
#define NBC 32768      // 2*DI*DS columns (B|C)
#define NCHUNK 128
#define TCHUNK 16      // L_SEQ / NCHUNK

using f32x4  = __attribute__((ext_vector_type(4))) float;
using bf16x8 = __attribute__((ext_vector_type(8))) short;

typedef const __attribute__((address_space(1))) void gas_void;
typedef __attribute__((address_space(3))) void las_void;

#define GLL16(gp, lp) __builtin_amdgcn_global_load_lds( \
    (gas_void*)(uintptr_t)(gp), (las_void*)(uintptr_t)(lp), 16, 0, 0)

#define VMCNT(n) asm volatile("s_waitcnt vmcnt(" #n ")" ::: "memory")
// rule #18: lgkmcnt drain + scheduling fence so MFMAs can't hoist above the wait
#define LGKM0 do { asm volatile("s_waitcnt lgkmcnt(0)" ::: "memory"); \
                   __builtin_amdgcn_sched_barrier(0); } while (0)

__device__ __forceinline__ unsigned short f2bf(float f) {
  unsigned u = __builtin_bit_cast(unsigned, f);
  u += 0x7fffu + ((u >> 16) & 1u);
  return (unsigned short)(u >> 16);
}
__device__ __forceinline__ float bflo(unsigned u) { return __builtin_bit_cast(float, u << 16); }
__device__ __forceinline__ float bfhi(unsigned u) { return __builtin_bit_cast(float, u & 0xffff0000u); }
__device__ __forceinline__ float softplusf(float z) {
  return (z > 20.f) ? z : log1pf(expf(z));
}

// ---------------- cast f32 -> bf16, 8 elems/thread ----------------
__global__ void cast_bf16_kernel(const float* __restrict__ in,
                                 unsigned short* __restrict__ out, int n8) {
  int i = blockIdx.x * blockDim.x + threadIdx.x;
  if (i >= n8) return;
  const f32x4* p = (const f32x4*)(in + (size_t)i * 8);
  f32x4 a = p[0], b = p[1];
  union { unsigned short us[8]; uint4 v; } r;
#pragma unroll
  for (int j = 0; j < 4; ++j) r.us[j] = f2bf(a[j]);
#pragma unroll
  for (int j = 0; j < 4; ++j) r.us[4 + j] = f2bf(b[j]);
  *(uint4*)(out + (size_t)i * 8) = r.v;
}

// ================= big GEMM: dbc = x(2048x1024) @ Wbc(32768x1024)^T =================
// 256x256 tile, 8 waves (2Mx4N, 128x64 per wave), BK=32, 4-deep LDS ring (128 KiB).
// v2: two-phase fine interleave per K-step (8 ds_read + 16 MFMA, 4 ds_read + 16 MFMA)
// with lgkmcnt(0)+sched_barrier fences and setprio around MFMA clusters (T5),
// counted vmcnt(8) (T4), bijective XCD swizzle (T1).
__global__ __launch_bounds__(512, 2) void gemm_big(
    const unsigned short* __restrict__ A,
    const unsigned short* __restrict__ Bm,
    unsigned short* __restrict__ C) {
  constexpr int K = 1024;
  constexpr int KT = 32;       // K-tiles of 32
  constexpr int LDC = NBC;
  constexpr int GRID_N = 128;  // 32768/256
  __shared__ unsigned short lds[65536];  // 4 bufs x (A 16KB + B 16KB) = 128 KiB

  const int tid = threadIdx.x;
  const int lane = tid & 63;
  const int wave = tid >> 6;
  const int wm = (wave >> 2) * 128;   // 2 M-wave-groups
  const int wn = (wave & 3) * 64;     // 4 N-wave-groups
  const int lr = lane & 15;
  const int lkx = ((lane >> 4) ^ (lr & 3)) << 4;  // swizzled in-row byte offset

  // bijective XCD swizzle: contiguous chunk per XCD
  const int b = blockIdx.x;
  const int per = gridDim.x >> 3;
  const int sw = (b & 7) * per + (b >> 3);
  const int m0 = (sw / GRID_N) * 256;
  const int n0 = (sw % GRID_N) * 256;

  // staging: linear LDS dest + inverse-swizzled global source (rule #21)
  const int r0 = tid >> 2;
  const int colsw = 8 * ((tid & 3) ^ (r0 & 3));
  const unsigned short* gA0 = A + (size_t)(m0 + r0) * K + colsw;
  const unsigned short* gA1 = gA0 + (size_t)128 * K;
  const unsigned short* gB0 = Bm + (size_t)(n0 + r0) * K + colsw;
  const unsigned short* gB1 = gB0 + (size_t)128 * K;

  f32x4 acc[8][4];
#pragma unroll
  for (int m = 0; m < 8; ++m)
#pragma unroll
    for (int n = 0; n < 4; ++n) acc[m][n] = f32x4{0.f, 0.f, 0.f, 0.f};

  auto stage = [&](int buf, int kt) {
    const int kofs = kt * 32;
    unsigned short* d = &lds[buf * 16384 + tid * 8];
    GLL16(gA0 + kofs, d);            // A half 0 (rows 0-127)
    GLL16(gA1 + kofs, d + 4096);     // A half 1 (rows 128-255)
    GLL16(gB0 + kofs, d + 8192);     // B half 0
    GLL16(gB1 + kofs, d + 12288);    // B half 1
  };

  auto compute = [&](int buf) {
    const char* base = (const char*)lds + (size_t)buf * 32768;
    const char* bb = base + 16384;
    // ---- phase 1: 8 ds_read (all B + A m=0..3), fence, 16 MFMA ----
    bf16x8 b0 = *(const bf16x8*)(bb + (wn +  0 + lr) * 64 + lkx);
    bf16x8 b1 = *(const bf16x8*)(bb + (wn + 16 + lr) * 64 + lkx);
    bf16x8 b2 = *(const bf16x8*)(bb + (wn + 32 + lr) * 64 + lkx);
    bf16x8 b3 = *(const bf16x8*)(bb + (wn + 48 + lr) * 64 + lkx);
    bf16x8 a0 = *(const bf16x8*)(base + (wm +  0 + lr) * 64 + lkx);
    bf16x8 a1 = *(const bf16x8*)(base + (wm + 16 + lr) * 64 + lkx);
    bf16x8 a2 = *(const bf16x8*)(base + (wm + 32 + lr) * 64 + lkx);
    bf16x8 a3 = *(const bf16x8*)(base + (wm + 48 + lr) * 64 + lkx);
    LGKM0;
    __builtin_amdgcn_s_setprio(1);
    acc[0][0] = __builtin_amdgcn_mfma_f32_16x16x32_bf16(a0, b0, acc[0][0], 0, 0, 0);
    acc[0][1] = __builtin_amdgcn_mfma_f32_16x16x32_bf16(a0, b1, acc[0][1], 0, 0, 0);
    acc[0][2] = __builtin_amdgcn_mfma_f32_16x16x32_bf16(a0, b2, acc[0][2], 0, 0, 0);
    acc[0][3] = __builtin_amdgcn_mfma_f32_16x16x32_bf16(a0, b3, acc[0][3], 0, 0, 0);
    acc[1][0] = __builtin_amdgcn_mfma_f32_16x16x32_bf16(a1, b0, acc[1][0], 0, 0, 0);
    acc[1][1] = __builtin_amdgcn_mfma_f32_16x16x32_bf16(a1, b1, acc[1][1], 0, 0, 0);
    acc[1][2] = __builtin_amdgcn_mfma_f32_16x16x32_bf16(a1, b2, acc[1][2], 0, 0, 0);
    acc[1][3] = __builtin_amdgcn_mfma_f32_16x16x32_bf16(a1, b3, acc[1][3], 0, 0, 0);
    acc[2][0] = __builtin_amdgcn_mfma_f32_16x16x32_bf16(a2, b0, acc[2][0], 0, 0, 0);
    acc[2][1] = __builtin_amdgcn_mfma_f32_16x16x32_bf16(a2, b1, acc[2][1], 0, 0, 0);
    acc[2][2] = __builtin_amdgcn_mfma_f32_16x16x32_bf16(a2, b2, acc[2][2], 0, 0, 0);
    acc[2][3] = __builtin_amdgcn_mfma_f32_16x16x32_bf16(a2, b3, acc[2][3], 0, 0, 0);
    acc[3][0] = __builtin_amdgcn_mfma_f32_16x16x32_bf16(a3, b0, acc[3][0], 0, 0, 0);
    acc[3][1] = __builtin_amdgcn_mfma_f32_16x16x32_bf16(a3, b1, acc[3][1], 0, 0, 0);
    acc[3][2] = __builtin_amdgcn_mfma_f32_16x16x32_bf16(a3, b2, acc[3][2], 0, 0, 0);
    acc[3][3] = __builtin_amdgcn_mfma_f32_16x16x32_bf16(a3, b3, acc[3][3], 0, 0, 0);
    __builtin_amdgcn_s_setprio(0);
    __builtin_amdgcn_sched_barrier(0);
    // ---- phase 2: 4 ds_read (A m=4..7), fence, 16 MFMA ----
    bf16x8 a4 = *(const bf16x8*)(base + (wm +  64 + lr) * 64 + lkx);
    bf16x8 a5 = *(const bf16x8*)(base + (wm +  80 + lr) * 64 + lkx);
    bf16x8 a6 = *(const bf16x8*)(base + (wm +  96 + lr) * 64 + lkx);
    bf16x8 a7 = *(const bf16x8*)(base + (wm + 112 + lr) * 64 + lkx);
    LGKM0;
    __builtin_amdgcn_s_setprio(1);
    acc[4][0] = __builtin_amdgcn_mfma_f32_16x16x32_bf16(a4, b0, acc[4][0], 0, 0, 0);
    acc[4][1] = __builtin_amdgcn_mfma_f32_16x16x32_bf16(a4, b1, acc[4][1], 0, 0, 0);
    acc[4][2] = __builtin_amdgcn_mfma_f32_16x16x32_bf16(a4, b2, acc[4][2], 0, 0, 0);
    acc[4][3] = __builtin_amdgcn_mfma_f32_16x16x32_bf16(a4, b3, acc[4][3], 0, 0, 0);
    acc[5][0] = __builtin_amdgcn_mfma_f32_16x16x32_bf16(a5, b0, acc[5][0], 0, 0, 0);
    acc[5][1] = __builtin_amdgcn_mfma_f32_16x16x32_bf16(a5, b1, acc[5][1], 0, 0, 0);
    acc[5][2] = __builtin_amdgcn_mfma_f32_16x16x32_bf16(a5, b2, acc[5][2], 0, 0, 0);
    acc[5][3] = __builtin_amdgcn_mfma_f32_16x16x32_bf16(a5, b3, acc[5][3], 0, 0, 0);
    acc[6][0] = __builtin_amdgcn_mfma_f32_16x16x32_bf16(a6, b0, acc[6][0], 0, 0, 0);
    acc[6][1] = __builtin_amdgcn_mfma_f32_16x16x32_bf16(a6, b1, acc[6][1], 0, 0, 0);
    acc[6][2] = __builtin_amdgcn_mfma_f32_16x16x32_bf16(a6, b2, acc[6][2], 0, 0, 0);
    acc[6][3] = __builtin_amdgcn_mfma_f32_16x16x32_bf16(a6, b3, acc[6][3], 0, 0, 0);
    acc[7][0] = __builtin_amdgcn_mfma_f32_16x16x32_bf16(a7, b0, acc[7][0], 0, 0, 0);
    acc[7][1] = __builtin_amdgcn_mfma_f32_16x16x32_bf16(a7, b1, acc[7][1], 0, 0, 0);
    acc[7][2] = __builtin_amdgcn_mfma_f32_16x16x32_bf16(a7, b2, acc[7][2], 0, 0, 0);
    acc[7][3] = __builtin_amdgcn_mfma_f32_16x16x32_bf16(a7, b3, acc[7][3], 0, 0, 0);
    __builtin_amdgcn_s_setprio(0);
  };

  // prologue: 3 tiles in flight, wait for tile 0 (12 issued, vmcnt(8) -> oldest 4 done)
  stage(0, 0);
  stage(1, 1);
  stage(2, 2);
  VMCNT(8);
  __builtin_amdgcn_s_barrier();
  __builtin_amdgcn_sched_barrier(0);

#pragma unroll 4
  for (int t = 0; t < KT - 3; ++t) {
    stage((t + 3) & 3, t + 3);   // writes buffer last read at t-1 (barrier-protected)
    compute(t & 3);
    VMCNT(8);                    // tiles {t+2,t+3} may remain in flight; t+1 landed
    __builtin_amdgcn_s_barrier();
    __builtin_amdgcn_sched_barrier(0);
  }
  compute((KT - 3) & 3);
  VMCNT(4);
  __builtin_amdgcn_s_barrier();
  __builtin_amdgcn_sched_barrier(0);
  compute((KT - 2) & 3);
  VMCNT(0);
  __builtin_amdgcn_s_barrier();
  __builtin_amdgcn_sched_barrier(0);
  compute((KT - 1) & 3);

  // epilogue: C/D mapping col=lane&15, row=(lane>>4)*4+r (m89/m91-verified)
  const int crow = (lane >> 4) * 4;
#pragma unroll
  for (int m = 0; m < 8; ++m)
#pragma unroll
    for (int n = 0; n < 4; ++n)
#pragma unroll
      for (int r = 0; r < 4; ++r) {
        int row = m0 + wm + m * 16 + crow + r;
        int col = n0 + wn + n * 16 + lr;
        C[(size_t)row * LDC + col] = f2bf(acc[m][n][r]);
      }
}

// ---------------- output GEMM: out(2048x1024 f32) = y_bf @ Wout_bf^T ----------------
// 128x64 tile -> 256 WGs (full GPU). m97 2-barrier structure; inputs are L2-resident.
__global__ __launch_bounds__(256) void gemm_out(
    const unsigned short* __restrict__ A,
    const unsigned short* __restrict__ Bm,
    float* __restrict__ C) {
  constexpr int K = DI;
  __shared__ unsigned short As[128 * 32];
  __shared__ unsigned short Bs[64 * 32];
  const int tid = threadIdx.x;
  const int lane = tid & 63;
  const int wave = tid >> 6;
  const int wm = (wave >> 1) * 64, wn = (wave & 1) * 32;
  const int m0 = blockIdx.y * 128, n0 = blockIdx.x * 64;
  const int lr = lane & 15, lk = (lane >> 4) * 8;

  const int srow = tid >> 2;
  const int scol = (tid & 3) * 8;
  const unsigned short* gA = A + (size_t)(m0 + srow) * K + scol;
  const unsigned short* gB = Bm + (size_t)(n0 + srow) * K + scol;
  unsigned short* lA0 = &As[tid * 8];
  unsigned short* lA1 = &As[2048 + tid * 8];
  unsigned short* lB  = &Bs[tid * 8];

  f32x4 acc[4][2];
#pragma unroll
  for (int m = 0; m < 4; ++m)
#pragma unroll
    for (int n = 0; n < 2; ++n) acc[m][n] = f32x4{0.f, 0.f, 0.f, 0.f};

  for (int k0 = 0; k0 < K; k0 += 32) {
    GLL16(gA + k0, lA0);
    GLL16(gA + (size_t)64 * K + k0, lA1);
    GLL16(gB + k0, lB);
    __syncthreads();
    bf16x8 af[4], bv[2];
#pragma unroll
    for (int m = 0; m < 4; ++m)
      af[m] = *(const bf16x8*)&As[(wm + m * 16 + lr) * 32 + lk];
#pragma unroll
    for (int n = 0; n < 2; ++n)
      bv[n] = *(const bf16x8*)&Bs[(wn + n * 16 + lr) * 32 + lk];
#pragma unroll
    for (int m = 0; m < 4; ++m)
#pragma unroll
      for (int n = 0; n < 2; ++n)
        acc[m][n] = __builtin_amdgcn_mfma_f32_16x16x32_bf16(af[m], bv[n], acc[m][n], 0, 0, 0);
    __syncthreads();
  }

  const int crow = (lane >> 4) * 4;
#pragma unroll
  for (int m = 0; m < 4; ++m)
#pragma unroll
    for (int n = 0; n < 2; ++n)
#pragma unroll
      for (int r = 0; r < 4; ++r) {
        int row = m0 + wm + m * 16 + crow + r;
        int col = n0 + wn + n * 16 + lr;
        C[(size_t)row * DM + col] = acc[m][n][r];
      }
}

// ---------------- delta_lr = x @ W_in[0:64].T  (fp32, exact path) ----------------
__global__ __launch_bounds__(256) void delta_lr_kernel(
    const float* __restrict__ x, const float* __restrict__ Win,
    float* __restrict__ dlr) {
  __shared__ float xs[16][65];
  __shared__ float ws[64][65];
  const int tid = threadIdx.x;
  const int t0 = blockIdx.x * 16;
  const int r = tid & 63, tg = tid >> 6;
  float a0 = 0.f, a1 = 0.f, a2 = 0.f, a3 = 0.f;
  for (int k0 = 0; k0 < DM; k0 += 64) {
    {
      int row = tid >> 4, col = (tid & 15) * 4;
      f32x4 v = *(const f32x4*)&x[(size_t)(t0 + row) * DM + k0 + col];
      xs[row][col] = v.x; xs[row][col + 1] = v.y; xs[row][col + 2] = v.z; xs[row][col + 3] = v.w;
    }
#pragma unroll
    for (int p = 0; p < 4; ++p) {
      int idx = tid + p * 256;
      int row = idx >> 4, col = (idx & 15) * 4;
      f32x4 v = *(const f32x4*)&Win[(size_t)row * DM + k0 + col];
      ws[row][col] = v.x; ws[row][col + 1] = v.y; ws[row][col + 2] = v.z; ws[row][col + 3] = v.w;
    }
    __syncthreads();
#pragma unroll 16
    for (int kk = 0; kk < 64; ++kk) {
      float wv = ws[r][kk];
      a0 += xs[tg * 4 + 0][kk] * wv;
      a1 += xs[tg * 4 + 1][kk] * wv;
      a2 += xs[tg * 4 + 2][kk] * wv;
      a3 += xs[tg * 4 + 3][kk] * wv;
    }
    __syncthreads();
  }
  dlr[(size_t)(t0 + tg * 4 + 0) * RK + r] = a0;
  dlr[(size_t)(t0 + tg * 4 + 1) * RK + r] = a1;
  dlr[(size_t)(t0 + tg * 4 + 2) * RK + r] = a2;
  dlr[(size_t)(t0 + tg * 4 + 3) * RK + r] = a3;
}

// ---------------- delta = softplus(delta_lr @ W_delta.T)  (fp32) ----------------
__global__ __launch_bounds__(256) void delta_kernel(
    const float* __restrict__ dlr, const float* __restrict__ Wd,
    float* __restrict__ delta) {
  __shared__ float dl[16][65];
  __shared__ float wd[64][65];
  const int tid = threadIdx.x;
  const int i0 = blockIdx.x * 64;
  const int t0 = blockIdx.y * 16;
  const int il = tid & 63, tg = tid >> 6;
  {
    int row = tid >> 4, col = (tid & 15) * 4;
    f32x4 v = *(const f32x4*)&dlr[(size_t)(t0 + row) * RK + col];
    dl[row][col] = v.x; dl[row][col + 1] = v.y; dl[row][col + 2] = v.z; dl[row][col + 3] = v.w;
  }
#pragma unroll
  for (int p = 0; p < 4; ++p) {
    int idx = tid + p * 256;
    int row = idx >> 4, col = (idx & 15) * 4;
    f32x4 v = *(const f32x4*)&Wd[(size_t)(i0 + row) * RK + col];
    wd[row][col] = v.x; wd[row][col + 1] = v.y; wd[row][col + 2] = v.z; wd[row][col + 3] = v.w;
  }
  __syncthreads();
  float a0 = 0.f, a1 = 0.f, a2 = 0.f, a3 = 0.f;
#pragma unroll 16
  for (int kk = 0; kk < 64; ++kk) {
    float wv = wd[il][kk];
    a0 += dl[tg * 4 + 0][kk] * wv;
    a1 += dl[tg * 4 + 1][kk] * wv;
    a2 += dl[tg * 4 + 2][kk] * wv;
    a3 += dl[tg * 4 + 3][kk] * wv;
  }
  delta[(size_t)(t0 + tg * 4 + 0) * DI + i0 + il] = softplusf(a0);
  delta[(size_t)(t0 + tg * 4 + 1) * DI + i0 + il] = softplusf(a1);
  delta[(size_t)(t0 + tg * 4 + 2) * DI + i0 + il] = softplusf(a2);
  delta[(size_t)(t0 + tg * 4 + 3) * DI + i0 + il] = softplusf(a3);
}

// ---------------- scan pass 1: per-chunk local scan (h from 0), store h_end, P_end ----------------
__global__ __launch_bounds__(256) void scan_pass1(
    const float* __restrict__ delta, const float* __restrict__ x,
    const unsigned short* __restrict__ dbc, const float* __restrict__ A_log,
    float* __restrict__ h_end, float* __restrict__ P_end) {
  const int c = blockIdx.x >> 2;
  const int d = ((blockIdx.x & 3) << 8) + threadIdx.x;
  float Av[16];
#pragma unroll
  for (int q = 0; q < 4; ++q) {
    f32x4 v = *(const f32x4*)&A_log[(size_t)d * 16 + q * 4];
    Av[q * 4 + 0] = -expf(v.x); Av[q * 4 + 1] = -expf(v.y);
    Av[q * 4 + 2] = -expf(v.z); Av[q * 4 + 3] = -expf(v.w);
  }
  float h[16], P[16];
#pragma unroll
  for (int s = 0; s < 16; ++s) { h[s] = 0.f; P[s] = 1.f; }
  const int t0 = c * TCHUNK, t1 = t0 + TCHUNK;
  uint4 b0 = *(const uint4*)&dbc[(size_t)t0 * NBC + d * 16];
  uint4 b1 = *(const uint4*)&dbc[(size_t)t0 * NBC + d * 16 + 8];
  float dlt = delta[(size_t)t0 * DI + d];
  float xv = x[(size_t)t0 * DI + d];
  for (int t = t0; t < t1; ++t) {
    int tn = (t + 1 < t1) ? t + 1 : t;
    uint4 nb0 = *(const uint4*)&dbc[(size_t)tn * NBC + d * 16];
    uint4 nb1 = *(const uint4*)&dbc[(size_t)tn * NBC + d * 16 + 8];
    float ndlt = delta[(size_t)tn * DI + d];
    float nxv = x[(size_t)tn * DI + d];
    float du = dlt * xv;
    unsigned bu[8] = {b0.x, b0.y, b0.z, b0.w, b1.x, b1.y, b1.z, b1.w};
#pragma unroll
    for (int s = 0; s < 16; ++s) {
      float dA = __expf(dlt * Av[s]);
      float Bv = (s & 1) ? bfhi(bu[s >> 1]) : bflo(bu[s >> 1]);
      h[s] = dA * h[s] + du * Bv;
      P[s] *= dA;
    }
    b0 = nb0; b1 = nb1; dlt = ndlt; xv = nxv;
  }
  float* he = &h_end[((size_t)c * DI + d) * 16];
  float* pe = &P_end[((size_t)c * DI + d) * 16];
#pragma unroll
  for (int q = 0; q < 4; ++q) {
    f32x4 vh = {h[q * 4 + 0], h[q * 4 + 1], h[q * 4 + 2], h[q * 4 + 3]};
    f32x4 vp = {P[q * 4 + 0], P[q * 4 + 1], P[q * 4 + 2], P[q * 4 + 3]};
    *(f32x4*)&he[q * 4] = vh;
    *(f32x4*)&pe[q * 4] = vp;
  }
}

// ---------------- scan pass 2: combine chunk boundaries ----------------
__global__ void scan_pass2(const float* __restrict__ h_end,
                           const float* __restrict__ P_end,
                           float* __restrict__ h_in) {
  const int j = blockIdx.x * 256 + threadIdx.x;  // 0 .. DI*DS-1
  const int NS = DI * DS;
  float h = 0.f;
  for (int c = 0; c < NCHUNK; c += 4) {
    float P0 = P_end[(size_t)(c + 0) * NS + j], H0 = h_end[(size_t)(c + 0) * NS + j];
    float P1 = P_end[(size_t)(c + 1) * NS + j], H1 = h_end[(size_t)(c + 1) * NS + j];
    float P2 = P_end[(size_t)(c + 2) * NS + j], H2 = h_end[(size_t)(c + 2) * NS + j];
    float P3 = P_end[(size_t)(c + 3) * NS + j], H3 = h_end[(size_t)(c + 3) * NS + j];
    h_in[(size_t)(c + 0) * NS + j] = h; h = P0 * h + H0;
    h_in[(size_t)(c + 1) * NS + j] = h; h = P1 * h + H1;
    h_in[(size_t)(c + 2) * NS + j] = h; h = P2 * h + H2;
    h_in[(size_t)(c + 3) * NS + j] = h; h = P3 * h + H3;
  }
}

// ---------------- scan pass 3: full scan from h_in, emit y (bf16) ----------------
__global__ __launch_bounds__(256) void scan_pass3(
    const float* __restrict__ delta, const float* __restrict__ x,
    const unsigned short* __restrict__ dbc, const float* __restrict__ A_log,
    const float* __restrict__ Dvec, const float* __restrict__ h_in,
    unsigned short* __restrict__ ybf) {
  const int c = blockIdx.x >> 2;
  const int d = ((blockIdx.x & 3) << 8) + threadIdx.x;
  float Av[16];
#pragma unroll
  for (int q = 0; q < 4; ++q) {
    f32x4 v = *(const f32x4*)&A_log[(size_t)d * 16 + q * 4];
    Av[q * 4 + 0] = -expf(v.x); Av[q * 4 + 1] = -expf(v.y);
    Av[q * 4 + 2] = -expf(v.z); Av[q * 4 + 3] = -expf(v.w);
  }
  const float Df = Dvec[d];
  float h[16];
  const float* hi = &h_in[((size_t)c * DI + d) * 16];
#pragma unroll
  for (int q = 0; q < 4; ++q) {
    f32x4 v = *(const f32x4*)&hi[q * 4];
    h[q * 4 + 0] = v.x; h[q * 4 + 1] = v.y; h[q * 4 + 2] = v.z; h[q * 4 + 3] = v.w;
  }
  const int t0 = c * TCHUNK, t1 = t0 + TCHUNK;
  uint4 b0 = *(const uint4*)&dbc[(size_t)t0 * NBC + d * 16];
  uint4 b1 = *(const uint4*)&dbc[(size_t)t0 * NBC + d * 16 + 8];
  uint4 c0 = *(const uint4*)&dbc[(size_t)t0 * NBC + DI * DS + d * 16];
  uint4 c1 = *(const uint4*)&dbc[(size_t)t0 * NBC + DI * DS + d * 16 + 8];
  float dlt = delta[(size_t)t0 * DI + d];
  float xv = x[(size_t)t0 * DI + d];
  for (int t = t0; t < t1; ++t) {
    int tn = (t + 1 < t1) ? t + 1 : t;
    uint4 nb0 = *(const uint4*)&dbc[(size_t)tn * NBC + d * 16];
    uint4 nb1 = *(const uint4*)&dbc[(size_t)tn * NBC + d * 16 + 8];
    uint4 nc0 = *(const uint4*)&dbc[(size_t)tn * NBC + DI * DS + d * 16];
    uint4 nc1 = *(const uint4*)&dbc[(size_t)tn * NBC + DI * DS + d * 16 + 8];
    float ndlt = delta[(size_t)tn * DI + d];
    float nxv = x[(size_t)tn * DI + d];
    float du = dlt * xv;
    unsigned bu[8] = {b0.x, b0.y, b0.z, b0.w, b1.x, b1.y, b1.z, b1.w};
    unsigned cu[8] = {c0.x, c0.y, c0.z, c0.w, c1.x, c1.y, c1.z, c1.w};
    float yacc = 0.f;
#pragma unroll
    for (int s = 0; s < 16; ++s) {
      float dA = __expf(dlt * Av[s]);
      float Bv = (s & 1) ? bfhi(bu[s >> 1]) : bflo(bu[s >> 1]);
      float Cv = (s & 1) ? bfhi(cu[s >> 1]) : bflo(cu[s >> 1]);
      h[s] = dA * h[s] + du * Bv;
      yacc += h[s] * Cv;
    }
    ybf[(size_t)t * DI + d] = f2bf(yacc + xv * Df);
    b0 = nb0; b1 = nb1; c0 = nc0; c1 = nc1; dlt = ndlt; xv = nxv;
  }
}

// ---------------- launch ----------------
extern "C" void kernel_launch(void* const* d_in, const int* in_sizes, int n_in,
                              void* d_out, int out_size, void* d_ws, size_t ws_size,
                              hipStream_t stream) {
  const float* x    = (const float*)d_in[0];
  const float* Win  = (const float*)d_in[1];
  const float* Wd   = (const float*)d_in[2];
  const float* Alog = (const float*)d_in[3];
  const float* Dv   = (const float*)d_in[4];
  const float* Wout = (const float*)d_in[5];
  float* out = (float*)d_out;

  char* ws = (char*)d_ws;
  size_t off = 0;
  auto walloc = [&](size_t bytes) -> void* {
    void* p = ws + off;
    off += (bytes + 255) & ~(size_t)255;
    return p;
  };
  unsigned short* x_bf    = (unsigned short*)walloc((size_t)L_SEQ * DI * 2);
  unsigned short* Wbc_bf  = (unsigned short*)walloc((size_t)NBC * DM * 2);
  unsigned short* Wout_bf = (unsigned short*)walloc((size_t)DM * DI * 2);
  unsigned short* dbc     = (unsigned short*)walloc((size_t)L_SEQ * NBC * 2);
  float* dlr   = (float*)walloc((size_t)L_SEQ * RK * 4);
  float* delta = (float*)walloc((size_t)L_SEQ * DI * 4);
  unsigned short* y_bf = (unsigned short*)walloc((size_t)L_SEQ * DI * 2);
  float* h_end = (float*)walloc((size_t)NCHUNK * DI * DS * 4);
  float* P_end = (float*)walloc((size_t)NCHUNK * DI * DS * 4);
  float* h_in  = (float*)walloc((size_t)NCHUNK * DI * DS * 4);

  // casts
  cast_bf16_kernel<<<(L_SEQ * DI / 8 + 255) / 256, 256, 0, stream>>>(x, x_bf, L_SEQ * DI / 8);
  cast_bf16_kernel<<<((size_t)NBC * DM / 8 + 255) / 256, 256, 0, stream>>>(
      Win + (size_t)RK * DM, Wbc_bf, NBC * DM / 8);
  cast_bf16_kernel<<<(DM * DI / 8 + 255) / 256, 256, 0, stream>>>(Wout, Wout_bf, DM * DI / 8);

  // fp32 delta path
  delta_lr_kernel<<<L_SEQ / 16, 256, 0, stream>>>(x, Win, dlr);
  delta_kernel<<<dim3(DI / 64, L_SEQ / 16), 256, 0, stream>>>(dlr, Wd, delta);

  // big bf16 GEMM: dbc(B|C) = x @ W_in[64:].T   (256^2 tile, 8-wave, ring-buffered)
  gemm_big<<<(L_SEQ / 256) * (NBC / 256), 512, 0, stream>>>(x_bf, Wbc_bf, dbc);

  // chunked scan
  scan_pass1<<<NCHUNK * 4, 256, 0, stream>>>(delta, x, dbc, Alog, h_end, P_end);
  scan_pass2<<<DI * DS / 256, 256, 0, stream>>>(h_end, P_end, h_in);
  scan_pass3<<<NCHUNK * 4, 256, 0, stream>>>(delta, x, dbc, Alog, Dv, h_in, y_bf);

  // output GEMM: out = y @ W_out.T
  gemm_out<<<dim3(DM / 64, L_SEQ / 128), 256, 0, stream>>>(y_bf, Wout_bf, out);
}